// Round 3
// baseline (126.387 us; speedup 1.0000x reference)
//
#include <hip/hip_runtime.h>
#include <math.h>

// Output = relu(relu(h2[t=6]) @ Wlin^T + b) -> only 7 LSTM steps matter.
//
// R3: LDS-issue-bound fix. Quad = 4 gate types (i,f,g,o) of one unit need the
// SAME h data: lane q reads one float4 chunk, 3 DPP quad-rotations circulate
// all 4 chunks (VALU pipe instead of LDS pipe). Weights loaded per-lane in
// ROTATED chunk order so FMA weight indices stay compile-time static.
// x-contribution (W_ih0 x + bias) precomputed into registers in the prologue.
// In-loop LDS: 12 ds_read_b128 / lane / step (was 83 ds_read_b64).

constexpr int kT  = 7;
constexpr int kI  = 23;
constexpr int kH  = 20;
constexpr int kG  = 80;
constexpr int kBT = 8;     // batch tile per block
constexpr int kThreads = 320;
constexpr int kXP = 24;    // padded x row (23 + zero pad)

__device__ __forceinline__ float sigm(float v) {
    return __builtin_amdgcn_rcpf(1.0f + __builtin_amdgcn_exp2f(v * -1.44269504f));
}
__device__ __forceinline__ float tanh_(float v) {
    return 1.0f - 2.0f * __builtin_amdgcn_rcpf(__builtin_amdgcn_exp2f(v * 2.88539008f) + 1.0f);
}
template<int J>
__device__ __forceinline__ float qb(float v) {   // broadcast quad lane J
    return __int_as_float(__builtin_amdgcn_mov_dpp(__float_as_int(v), J * 0x55, 0xF, 0xF, true));
}
__device__ __forceinline__ float rotl(float v) { // lane q <- lane (q+1)&3
    return __int_as_float(__builtin_amdgcn_mov_dpp(__float_as_int(v), 0x39, 0xF, 0xF, true));
}
__device__ __forceinline__ float4 rot4(float4 v) {
    return make_float4(rotl(v.x), rotl(v.y), rotl(v.z), rotl(v.w));
}
__device__ __forceinline__ void lstm_update(float a, float& c, float& h) {
    const float gi = qb<0>(a), gf = qb<1>(a), gg = qb<2>(a), go = qb<3>(a);
    c = sigm(gf) * c + sigm(gi) * tanh_(gg);
    h = sigm(go) * tanh_(c);
}

// 20-float LDS row (16B-aligned, stride-20 layout) dot rotated weights w[0..19]
__device__ __forceinline__ float dot20(const float* __restrict__ row, const float* w, int q4) {
    float4 v = *reinterpret_cast<const float4*>(row + q4);     // own chunk (c = q)
    float a0 = 0.f, a1 = 0.f;
    a0 = fmaf(w[0],  v.x, a0); a1 = fmaf(w[1],  v.y, a1);
    a0 = fmaf(w[2],  v.z, a0); a1 = fmaf(w[3],  v.w, a1);
    v = rot4(v);                                               // chunk q+1
    a0 = fmaf(w[4],  v.x, a0); a1 = fmaf(w[5],  v.y, a1);
    a0 = fmaf(w[6],  v.z, a0); a1 = fmaf(w[7],  v.w, a1);
    v = rot4(v);                                               // chunk q+2
    a0 = fmaf(w[8],  v.x, a0); a1 = fmaf(w[9],  v.y, a1);
    a0 = fmaf(w[10], v.z, a0); a1 = fmaf(w[11], v.w, a1);
    v = rot4(v);                                               // chunk q+3
    a0 = fmaf(w[12], v.x, a0); a1 = fmaf(w[13], v.y, a1);
    a0 = fmaf(w[14], v.z, a0); a1 = fmaf(w[15], v.w, a1);
    const float4 t = *reinterpret_cast<const float4*>(row + 16); // tail k=16..19 (broadcast)
    a0 = fmaf(w[16], t.x, a0); a1 = fmaf(w[17], t.y, a1);
    a0 = fmaf(w[18], t.z, a0); a1 = fmaf(w[19], t.w, a1);
    return a0 + a1;
}

// 24-float padded LDS row dot rotated weights w[0..23] (w[23] = 0)
__device__ __forceinline__ float dot24(const float* __restrict__ row, const float* w, int q4) {
    float4 v = *reinterpret_cast<const float4*>(row + q4);
    float a0 = 0.f, a1 = 0.f;
    a0 = fmaf(w[0],  v.x, a0); a1 = fmaf(w[1],  v.y, a1);
    a0 = fmaf(w[2],  v.z, a0); a1 = fmaf(w[3],  v.w, a1);
    v = rot4(v);
    a0 = fmaf(w[4],  v.x, a0); a1 = fmaf(w[5],  v.y, a1);
    a0 = fmaf(w[6],  v.z, a0); a1 = fmaf(w[7],  v.w, a1);
    v = rot4(v);
    a0 = fmaf(w[8],  v.x, a0); a1 = fmaf(w[9],  v.y, a1);
    a0 = fmaf(w[10], v.z, a0); a1 = fmaf(w[11], v.w, a1);
    v = rot4(v);
    a0 = fmaf(w[12], v.x, a0); a1 = fmaf(w[13], v.y, a1);
    a0 = fmaf(w[14], v.z, a0); a1 = fmaf(w[15], v.w, a1);
    const float4 t4 = *reinterpret_cast<const float4*>(row + 16); // k 16..19
    a0 = fmaf(w[16], t4.x, a0); a1 = fmaf(w[17], t4.y, a1);
    a0 = fmaf(w[18], t4.z, a0); a1 = fmaf(w[19], t4.w, a1);
    const float4 t5 = *reinterpret_cast<const float4*>(row + 20); // k 20..22 + pad
    a0 = fmaf(w[20], t5.x, a0); a1 = fmaf(w[21], t5.y, a1);
    a0 = fmaf(w[22], t5.z, a0); a1 = fmaf(w[23], t5.w, a1);      // w[23]=0, pad=0
    return a0 + a1;
}

__global__ __launch_bounds__(kThreads, 3) void lstm7_kernel(
    const float* __restrict__ x,
    const float* __restrict__ h0,
    const float* __restrict__ c0,
    const float* __restrict__ Wih0,
    const float* __restrict__ Whh0,
    const float* __restrict__ bih0,
    const float* __restrict__ bhh0,
    const float* __restrict__ Wih1,
    const float* __restrict__ Whh1,
    const float* __restrict__ bih1,
    const float* __restrict__ bhh1,
    const float* __restrict__ Wlin,
    const float* __restrict__ blin,
    float* __restrict__ out,
    int B)
{
    __shared__ __align__(16) float xS[kT][kBT][kXP];   // [t][b][k], pad k=23 -> 0
    __shared__ __align__(16) float h1S[2][kBT][kH];    // [buf][b][u]
    __shared__ __align__(16) float h2S[2][kBT][kH];

    const int tid = threadIdx.x;
    const int b0  = blockIdx.x * kBT;
    const int bp  = tid / kG;          // batch pair 0..3
    const int q   = tid & 3;           // gate type
    const int u   = (tid % kG) >> 2;   // unit 0..19
    const int grow = q * kH + u;       // row in pytorch gate order i,f,g,o
    const int bb  = bp * 2;
    const int q4  = q * 4;

    // ---- stage x[t<7] (b-major rows) + zero pad ----
    for (int idx = tid; idx < kT * kBT * kI; idx += kThreads) {
        const int t = idx / (kBT * kI);
        const int r = idx % (kBT * kI);
        const int b = r / kI;
        const int i = r % kI;
        xS[t][b][i] = x[((size_t)t * B + b0 + b) * kI + i];
    }
    if (tid < kT * kBT) xS[tid / kBT][tid % kBT][kI] = 0.0f;

    // ---- stage initial h (buffer 0) ----
    if (tid < kH * kBT) {
        const int b = tid / kH, uu = tid % kH;
        h1S[0][b][uu] = h0[(size_t)(b0 + b) * kH + uu];
        h2S[0][b][uu] = h0[(size_t)(B + b0 + b) * kH + uu];
    }

    // ---- weights -> registers, ROTATED chunk order (chunk seq: q,q+1,q+2,q+3) ----
    float wA[24], wB[kH], wC[kH], wD[kH];
    {
        const float* WA = Wih0 + grow * kI;
#pragma unroll
        for (int r = 0; r < 4; ++r) {
            const int c = (q + r) & 3;
            wA[4*r+0] = WA[4*c+0]; wA[4*r+1] = WA[4*c+1];
            wA[4*r+2] = WA[4*c+2]; wA[4*r+3] = WA[4*c+3];
        }
        wA[16] = WA[16]; wA[17] = WA[17]; wA[18] = WA[18]; wA[19] = WA[19];
        wA[20] = WA[20]; wA[21] = WA[21]; wA[22] = WA[22]; wA[23] = 0.0f;

        const float4* PB = reinterpret_cast<const float4*>(Whh0 + grow * kH);
        const float4* PC = reinterpret_cast<const float4*>(Wih1 + grow * kH);
        const float4* PD = reinterpret_cast<const float4*>(Whh1 + grow * kH);
#pragma unroll
        for (int r = 0; r < 4; ++r) {
            const int c = (q + r) & 3;
            const float4 vb = PB[c], vc = PC[c], vd = PD[c];
            wB[4*r+0]=vb.x; wB[4*r+1]=vb.y; wB[4*r+2]=vb.z; wB[4*r+3]=vb.w;
            wC[4*r+0]=vc.x; wC[4*r+1]=vc.y; wC[4*r+2]=vc.z; wC[4*r+3]=vc.w;
            wD[4*r+0]=vd.x; wD[4*r+1]=vd.y; wD[4*r+2]=vd.z; wD[4*r+3]=vd.w;
        }
        const float4 tb = PB[4], tc = PC[4], td = PD[4];
        wB[16]=tb.x; wB[17]=tb.y; wB[18]=tb.z; wB[19]=tb.w;
        wC[16]=tc.x; wC[17]=tc.y; wC[18]=tc.z; wC[19]=tc.w;
        wD[16]=td.x; wD[17]=td.y; wD[18]=td.z; wD[19]=td.w;
    }
    const float bias1 = bih0[grow] + bhh0[grow];
    const float bias2 = bih1[grow] + bhh1[grow];

    // ---- c state (2 batches per lane, replicated across quad) ----
    float c1x = c0[(size_t)(b0 + bb) * kH + u];
    float c1y = c0[(size_t)(b0 + bb + 1) * kH + u];
    float c2x = c0[(size_t)(B + b0 + bb) * kH + u];
    float c2y = c0[(size_t)(B + b0 + bb + 1) * kH + u];

    __syncthreads();

    // ---- prologue: xg[t] = bias1 + W_ih0 . x[t]  (parallel over t, stays in regs) ----
    float xg0[kT], xg1[kT];
#pragma unroll
    for (int t = 0; t < kT; ++t) {
        xg0[t] = bias1 + dot24(&xS[t][bb][0],     wA, q4);
        xg1[t] = bias1 + dot24(&xS[t][bb + 1][0], wA, q4);
    }

    // ---- 7 timesteps, 2 layers, 2 barriers/step ----
#pragma unroll
    for (int t = 0; t < kT; ++t) {
        const int rb = t & 1, wb = rb ^ 1;

        // layer 1: gates = xg + W_hh0 . h1
        const float g0 = xg0[t] + dot20(&h1S[rb][bb][0],     wB, q4);
        const float g1 = xg1[t] + dot20(&h1S[rb][bb + 1][0], wB, q4);
        float h1x, h1y;
        lstm_update(g0, c1x, h1x);
        lstm_update(g1, c1y, h1y);
        if (q == 0) { h1S[wb][bb][u] = h1x; h1S[wb][bb + 1][u] = h1y; }
        __syncthreads();

        // layer 2: gates = bias2 + W_ih1 . h1_new + W_hh1 . h2_old
        const float s0 = bias2 + dot20(&h1S[wb][bb][0],     wC, q4)
                               + dot20(&h2S[rb][bb][0],     wD, q4);
        const float s1 = bias2 + dot20(&h1S[wb][bb + 1][0], wC, q4)
                               + dot20(&h2S[rb][bb + 1][0], wD, q4);
        float h2x, h2y;
        lstm_update(s0, c2x, h2x);
        lstm_update(s1, c2y, h2y);
        if (q == 0) { h2S[wb][bb][u] = h2x; h2S[wb][bb + 1][u] = h2y; }
        __syncthreads();
    }

    // ---- linear head on h2 of t=6 (buffer (6&1)^1 = 1) ----
    if (tid < kBT) {
        const int b = tid;
        float acc = blin[0];
#pragma unroll
        for (int uu = 0; uu < kH; ++uu) {
            acc = fmaf(fmaxf(h2S[1][b][uu], 0.0f), Wlin[uu], acc);
        }
        out[b0 + b] = fmaxf(acc, 0.0f);
    }
}

extern "C" void kernel_launch(void* const* d_in, const int* in_sizes, int n_in,
                              void* d_out, int out_size, void* d_ws, size_t ws_size,
                              hipStream_t stream) {
    const float* x    = (const float*)d_in[0];
    const float* h0   = (const float*)d_in[1];
    const float* c0   = (const float*)d_in[2];
    const float* Wih0 = (const float*)d_in[3];
    const float* Whh0 = (const float*)d_in[4];
    const float* bih0 = (const float*)d_in[5];
    const float* bhh0 = (const float*)d_in[6];
    const float* Wih1 = (const float*)d_in[7];
    const float* Whh1 = (const float*)d_in[8];
    const float* bih1 = (const float*)d_in[9];
    const float* bhh1 = (const float*)d_in[10];
    const float* Wlin = (const float*)d_in[11];
    const float* blin = (const float*)d_in[12];
    float* out = (float*)d_out;

    const int B = in_sizes[1] / (2 * kH);  // h0 is [2, B, 20]
    const int blocks = B / kBT;            // 4096/8 = 512

    hipLaunchKernelGGL(lstm7_kernel, dim3(blocks), dim3(kThreads), 0, stream,
                       x, h0, c0, Wih0, Whh0, bih0, bhh0,
                       Wih1, Whh1, bih1, bhh1, Wlin, blin, out, B);
}

// Round 4
// 28.656 us; speedup vs baseline: 4.4104x; 4.4104x over previous
//
#include <hip/hip_runtime.h>
#include <math.h>

// Output = relu(relu(h2[t=6]) @ Wlin^T + b) -> only 7 LSTM steps matter.
//
// R4 = R3 (quad-DPP rotation, 12 ds_read_b128/lane/step) minus the register
// spill that killed R3:
//  - xg (input-gate precompute) lives in LDS [t][g][10-pad], written/read by
//    the same lane (no barrier needed)  -> -14 always-live VGPRs
//  - wB/wC/wD + c-state loaded AFTER the prologue so wA(24) is dead first
//  - __launch_bounds__(320, 2): allocator headroom, no spill (R3: VGPR=84 +
//    144 MB scratch writes under (320,3))

constexpr int kT  = 7;
constexpr int kI  = 23;
constexpr int kH  = 20;
constexpr int kG  = 80;
constexpr int kBT = 8;     // batch tile per block
constexpr int kThreads = 320;
constexpr int kXP = 24;    // padded x row
constexpr int kGP = 10;    // xg batch stride (pad 8->10: conflict-free quads)

__device__ __forceinline__ float sigm(float v) {
    return __builtin_amdgcn_rcpf(1.0f + __builtin_amdgcn_exp2f(v * -1.44269504f));
}
__device__ __forceinline__ float tanh_(float v) {
    return 1.0f - 2.0f * __builtin_amdgcn_rcpf(__builtin_amdgcn_exp2f(v * 2.88539008f) + 1.0f);
}
template<int J>
__device__ __forceinline__ float qb(float v) {   // broadcast quad lane J
    return __int_as_float(__builtin_amdgcn_mov_dpp(__float_as_int(v), J * 0x55, 0xF, 0xF, true));
}
__device__ __forceinline__ float rotl(float v) { // lane q <- lane (q+1)&3
    return __int_as_float(__builtin_amdgcn_mov_dpp(__float_as_int(v), 0x39, 0xF, 0xF, true));
}
__device__ __forceinline__ float4 rot4(float4 v) {
    return make_float4(rotl(v.x), rotl(v.y), rotl(v.z), rotl(v.w));
}
__device__ __forceinline__ void lstm_update(float a, float& c, float& h) {
    const float gi = qb<0>(a), gf = qb<1>(a), gg = qb<2>(a), go = qb<3>(a);
    c = sigm(gf) * c + sigm(gi) * tanh_(gg);
    h = sigm(go) * tanh_(c);
}

// 20-float LDS row dot rotated weights w[0..19]; lane reads chunk q, DPP
// rotations circulate chunks q+1..q+3; tail k=16..19 is a wave broadcast.
__device__ __forceinline__ float dot20(const float* __restrict__ row, const float* w, int q4) {
    float4 v = *reinterpret_cast<const float4*>(row + q4);
    float a0 = 0.f, a1 = 0.f;
    a0 = fmaf(w[0],  v.x, a0); a1 = fmaf(w[1],  v.y, a1);
    a0 = fmaf(w[2],  v.z, a0); a1 = fmaf(w[3],  v.w, a1);
    v = rot4(v);
    a0 = fmaf(w[4],  v.x, a0); a1 = fmaf(w[5],  v.y, a1);
    a0 = fmaf(w[6],  v.z, a0); a1 = fmaf(w[7],  v.w, a1);
    v = rot4(v);
    a0 = fmaf(w[8],  v.x, a0); a1 = fmaf(w[9],  v.y, a1);
    a0 = fmaf(w[10], v.z, a0); a1 = fmaf(w[11], v.w, a1);
    v = rot4(v);
    a0 = fmaf(w[12], v.x, a0); a1 = fmaf(w[13], v.y, a1);
    a0 = fmaf(w[14], v.z, a0); a1 = fmaf(w[15], v.w, a1);
    const float4 t = *reinterpret_cast<const float4*>(row + 16);
    a0 = fmaf(w[16], t.x, a0); a1 = fmaf(w[17], t.y, a1);
    a0 = fmaf(w[18], t.z, a0); a1 = fmaf(w[19], t.w, a1);
    return a0 + a1;
}

// 24-float padded row (pad=0, w[23]=0)
__device__ __forceinline__ float dot24(const float* __restrict__ row, const float* w, int q4) {
    float4 v = *reinterpret_cast<const float4*>(row + q4);
    float a0 = 0.f, a1 = 0.f;
    a0 = fmaf(w[0],  v.x, a0); a1 = fmaf(w[1],  v.y, a1);
    a0 = fmaf(w[2],  v.z, a0); a1 = fmaf(w[3],  v.w, a1);
    v = rot4(v);
    a0 = fmaf(w[4],  v.x, a0); a1 = fmaf(w[5],  v.y, a1);
    a0 = fmaf(w[6],  v.z, a0); a1 = fmaf(w[7],  v.w, a1);
    v = rot4(v);
    a0 = fmaf(w[8],  v.x, a0); a1 = fmaf(w[9],  v.y, a1);
    a0 = fmaf(w[10], v.z, a0); a1 = fmaf(w[11], v.w, a1);
    v = rot4(v);
    a0 = fmaf(w[12], v.x, a0); a1 = fmaf(w[13], v.y, a1);
    a0 = fmaf(w[14], v.z, a0); a1 = fmaf(w[15], v.w, a1);
    const float4 t4 = *reinterpret_cast<const float4*>(row + 16);
    a0 = fmaf(w[16], t4.x, a0); a1 = fmaf(w[17], t4.y, a1);
    a0 = fmaf(w[18], t4.z, a0); a1 = fmaf(w[19], t4.w, a1);
    const float4 t5 = *reinterpret_cast<const float4*>(row + 20);
    a0 = fmaf(w[20], t5.x, a0); a1 = fmaf(w[21], t5.y, a1);
    a0 = fmaf(w[22], t5.z, a0); a1 = fmaf(w[23], t5.w, a1);
    return a0 + a1;
}

__global__ __launch_bounds__(kThreads, 2) void lstm7_kernel(
    const float* __restrict__ x,
    const float* __restrict__ h0,
    const float* __restrict__ c0,
    const float* __restrict__ Wih0,
    const float* __restrict__ Whh0,
    const float* __restrict__ bih0,
    const float* __restrict__ bhh0,
    const float* __restrict__ Wih1,
    const float* __restrict__ Whh1,
    const float* __restrict__ bih1,
    const float* __restrict__ bhh1,
    const float* __restrict__ Wlin,
    const float* __restrict__ blin,
    float* __restrict__ out,
    int B)
{
    __shared__ __align__(16) float xS[kT][kBT][kXP];   // [t][b][k]
    __shared__ __align__(16) float xgS[kT][kG][kGP];   // [t][gate_row][b(pad)]
    __shared__ __align__(16) float h1S[2][kBT][kH];    // [buf][b][u]
    __shared__ __align__(16) float h2S[2][kBT][kH];

    const int tid = threadIdx.x;
    const int b0  = blockIdx.x * kBT;
    const int bp  = tid / kG;          // batch pair 0..3
    const int q   = tid & 3;           // gate type
    const int u   = (tid % kG) >> 2;   // unit 0..19
    const int grow = q * kH + u;       // pytorch gate order i,f,g,o
    const int bb  = bp * 2;
    const int q4  = q * 4;

    // ---- stage x[t<7] + zero pad ----
    for (int idx = tid; idx < kT * kBT * kI; idx += kThreads) {
        const int t = idx / (kBT * kI);
        const int r = idx % (kBT * kI);
        const int b = r / kI;
        const int i = r % kI;
        xS[t][b][i] = x[((size_t)t * B + b0 + b) * kI + i];
    }
    if (tid < kT * kBT) xS[tid / kBT][tid % kBT][kI] = 0.0f;

    // ---- stage initial h (buffer 0) ----
    if (tid < kH * kBT) {
        const int b = tid / kH, uu = tid % kH;
        h1S[0][b][uu] = h0[(size_t)(b0 + b) * kH + uu];
        h2S[0][b][uu] = h0[(size_t)(B + b0 + b) * kH + uu];
    }

    __syncthreads();

    // ---- prologue: xg = bias1 + W_ih0 . x  -> LDS (own-lane data) ----
    {
        float wA[24];
        const float* WA = Wih0 + grow * kI;
#pragma unroll
        for (int r = 0; r < 4; ++r) {
            const int c = (q + r) & 3;
            wA[4*r+0] = WA[4*c+0]; wA[4*r+1] = WA[4*c+1];
            wA[4*r+2] = WA[4*c+2]; wA[4*r+3] = WA[4*c+3];
        }
        wA[16] = WA[16]; wA[17] = WA[17]; wA[18] = WA[18]; wA[19] = WA[19];
        wA[20] = WA[20]; wA[21] = WA[21]; wA[22] = WA[22]; wA[23] = 0.0f;
        const float bias1 = bih0[grow] + bhh0[grow];
#pragma unroll
        for (int t = 0; t < kT; ++t) {
            const float g0 = bias1 + dot24(&xS[t][bb][0],     wA, q4);
            const float g1 = bias1 + dot24(&xS[t][bb + 1][0], wA, q4);
            *reinterpret_cast<float2*>(&xgS[t][grow][bb]) = make_float2(g0, g1);
        }
    }

    // ---- in-loop weights (rotated chunk order) + c-state, loaded after
    //      the prologue so wA's 24 regs are dead first ----
    float wB[kH], wC[kH], wD[kH];
    {
        const float4* PB = reinterpret_cast<const float4*>(Whh0 + grow * kH);
        const float4* PC = reinterpret_cast<const float4*>(Wih1 + grow * kH);
        const float4* PD = reinterpret_cast<const float4*>(Whh1 + grow * kH);
#pragma unroll
        for (int r = 0; r < 4; ++r) {
            const int c = (q + r) & 3;
            const float4 vb = PB[c], vc = PC[c], vd = PD[c];
            wB[4*r+0]=vb.x; wB[4*r+1]=vb.y; wB[4*r+2]=vb.z; wB[4*r+3]=vb.w;
            wC[4*r+0]=vc.x; wC[4*r+1]=vc.y; wC[4*r+2]=vc.z; wC[4*r+3]=vc.w;
            wD[4*r+0]=vd.x; wD[4*r+1]=vd.y; wD[4*r+2]=vd.z; wD[4*r+3]=vd.w;
        }
        const float4 tb = PB[4], tc = PC[4], td = PD[4];
        wB[16]=tb.x; wB[17]=tb.y; wB[18]=tb.z; wB[19]=tb.w;
        wC[16]=tc.x; wC[17]=tc.y; wC[18]=tc.z; wC[19]=tc.w;
        wD[16]=td.x; wD[17]=td.y; wD[18]=td.z; wD[19]=td.w;
    }
    const float bias2 = bih1[grow] + bhh1[grow];
    float c1x = c0[(size_t)(b0 + bb) * kH + u];
    float c1y = c0[(size_t)(b0 + bb + 1) * kH + u];
    float c2x = c0[(size_t)(B + b0 + bb) * kH + u];
    float c2y = c0[(size_t)(B + b0 + bb + 1) * kH + u];

    // ---- 7 timesteps, 2 layers, 2 barriers/step ----
#pragma unroll
    for (int t = 0; t < kT; ++t) {
        const int rb = t & 1, wb = rb ^ 1;

        // layer 1: gates = xg + W_hh0 . h1   (xg read back from own write)
        const float2 xg = *reinterpret_cast<const float2*>(&xgS[t][grow][bb]);
        const float g0 = xg.x + dot20(&h1S[rb][bb][0],     wB, q4);
        const float g1 = xg.y + dot20(&h1S[rb][bb + 1][0], wB, q4);
        float h1x, h1y;
        lstm_update(g0, c1x, h1x);
        lstm_update(g1, c1y, h1y);
        if (q == 0) { h1S[wb][bb][u] = h1x; h1S[wb][bb + 1][u] = h1y; }
        __syncthreads();

        // layer 2: gates = bias2 + W_ih1 . h1_new + W_hh1 . h2_old
        const float s0 = bias2 + dot20(&h1S[wb][bb][0],     wC, q4)
                               + dot20(&h2S[rb][bb][0],     wD, q4);
        const float s1 = bias2 + dot20(&h1S[wb][bb + 1][0], wC, q4)
                               + dot20(&h2S[rb][bb + 1][0], wD, q4);
        float h2x, h2y;
        lstm_update(s0, c2x, h2x);
        lstm_update(s1, c2y, h2y);
        if (q == 0) { h2S[wb][bb][u] = h2x; h2S[wb][bb + 1][u] = h2y; }
        __syncthreads();
    }

    // ---- linear head on h2 of t=6 (buffer 1) ----
    if (tid < kBT) {
        const int b = tid;
        float acc = blin[0];
#pragma unroll
        for (int uu = 0; uu < kH; ++uu) {
            acc = fmaf(fmaxf(h2S[1][b][uu], 0.0f), Wlin[uu], acc);
        }
        out[b0 + b] = fmaxf(acc, 0.0f);
    }
}

extern "C" void kernel_launch(void* const* d_in, const int* in_sizes, int n_in,
                              void* d_out, int out_size, void* d_ws, size_t ws_size,
                              hipStream_t stream) {
    const float* x    = (const float*)d_in[0];
    const float* h0   = (const float*)d_in[1];
    const float* c0   = (const float*)d_in[2];
    const float* Wih0 = (const float*)d_in[3];
    const float* Whh0 = (const float*)d_in[4];
    const float* bih0 = (const float*)d_in[5];
    const float* bhh0 = (const float*)d_in[6];
    const float* Wih1 = (const float*)d_in[7];
    const float* Whh1 = (const float*)d_in[8];
    const float* bih1 = (const float*)d_in[9];
    const float* bhh1 = (const float*)d_in[10];
    const float* Wlin = (const float*)d_in[11];
    const float* blin = (const float*)d_in[12];
    float* out = (float*)d_out;

    const int B = in_sizes[1] / (2 * kH);  // h0 is [2, B, 20]
    const int blocks = B / kBT;            // 4096/8 = 512

    hipLaunchKernelGGL(lstm7_kernel, dim3(blocks), dim3(kThreads), 0, stream,
                       x, h0, c0, Wih0, Whh0, bih0, bhh0,
                       Wih1, Whh1, bih1, bhh1, Wlin, blin, out, B);
}